// Round 5
// baseline (726.613 us; speedup 1.0000x reference)
//
#include <hip/hip_runtime.h>

#define K_OFF   8
#define R_PAIRS 62500
#define NPAIRS  500000
#define N_IN    500000
#define N_OUT   125000
#define CIN     64
#define COUT    128
#define BN_EPS  1e-4f
#define SCAN_ELEMS 4096
#define NSB_OUT 31           // ceil(N_OUT / 4096)
#define ATILES  2
#define OLD_TILES 8

typedef __bf16 bf16;
typedef __bf16 bf16x2 __attribute__((ext_vector_type(2)));
typedef __bf16 bf16x4 __attribute__((ext_vector_type(4)));
typedef __bf16 bf16x8 __attribute__((ext_vector_type(8)));
typedef float  f32x4  __attribute__((ext_vector_type(4)));
typedef unsigned int u32;

// ==================== BN statistics ====================
template<int C>
__global__ void bn_stats_kernel(const float* __restrict__ x, int n_rows,
                                float* __restrict__ sums /* [2C] */) {
    constexpr int CG = C / 4;
    int tid = blockIdx.x * blockDim.x + threadIdx.x;
    int nth = gridDim.x * blockDim.x;
    const float4* x4 = (const float4*)x;
    long n4 = (long)n_rows * CG;
    int cg = tid % CG;
    float s[4] = {0,0,0,0}, q[4] = {0,0,0,0};
    for (long i = tid; i < n4; i += nth) {
        float4 v = x4[i];
        float f[4] = {v.x, v.y, v.z, v.w};
        #pragma unroll
        for (int j = 0; j < 4; j++) { s[j] += f[j]; q[j] += f[j] * f[j]; }
    }
    __shared__ float acc[2 * C];
    for (int i = threadIdx.x; i < 2 * C; i += blockDim.x) acc[i] = 0.f;
    __syncthreads();
    #pragma unroll
    for (int j = 0; j < 4; j++) {
        atomicAdd(&acc[cg * 4 + j], s[j]);
        atomicAdd(&acc[C + cg * 4 + j], q[j]);
    }
    __syncthreads();
    for (int i = threadIdx.x; i < 2 * C; i += blockDim.x) atomicAdd(&sums[i], acc[i]);
}

template<int C>
__global__ void bn_finalize_kernel(const float* __restrict__ sums,
                                   const float* __restrict__ gamma,
                                   const float* __restrict__ beta,
                                   float inv_n, float* __restrict__ ss) {
    int c = threadIdx.x;
    if (c < C) {
        float m  = sums[c] * inv_n;
        float v  = sums[C + c] * inv_n - m * m;
        float sc = gamma[c] * rsqrtf(v + BN_EPS);
        ss[c]     = sc;
        ss[C + c] = beta[c] - m * sc;
    }
}

// ==================== BN apply + ReLU -> bf16 (fp32 in) ====================
template<int C>
__global__ void bn_apply_f32_kernel(const float* __restrict__ x, const float* __restrict__ ss,
                                    bf16* __restrict__ xo, long items /* rows*C/8 */) {
    constexpr int CG = C / 8;
    long i = (long)blockIdx.x * blockDim.x + threadIdx.x;
    long stride = (long)gridDim.x * blockDim.x;   // multiple of CG
    int cg = (int)(i % CG);
    float sc[8], sh[8];
    #pragma unroll
    for (int j = 0; j < 8; j++) { sc[j] = ss[cg*8+j]; sh[j] = ss[C + cg*8+j]; }
    for (; i < items; i += stride) {
        const float4* p = (const float4*)(x + i * 8);
        float4 a = p[0], b = p[1];
        float f[8] = {a.x,a.y,a.z,a.w,b.x,b.y,b.z,b.w};
        bf16x8 h;
        #pragma unroll
        for (int j = 0; j < 8; j++) h[j] = (bf16)fmaxf(f[j]*sc[j] + sh[j], 0.f);
        *(bf16x8*)(xo + i * 8) = h;
    }
}

// ==================== hist over out + (k,chunk) counts ====================
__global__ void histO_kernel(const int* __restrict__ oidx, u32* __restrict__ countO,
                             u32* __restrict__ kc /* cnt at +0 */, int C, int CH) {
    __shared__ u32 lc[64];
    int tid = threadIdx.x;
    if (tid < 64) lc[tid] = 0;
    __syncthreads();
    int p = blockIdx.x * blockDim.x + tid;
    int stride = gridDim.x * blockDim.x;
    for (; p < NPAIRS; p += stride) {
        int o = oidx[p];
        atomicAdd(&countO[o], 1u);
        atomicAdd(&lc[(p / R_PAIRS) * C + o / CH], 1u);
    }
    __syncthreads();
    if (tid < 64 && lc[tid]) atomicAdd(&kc[tid], lc[tid]);
}

// ==================== 3-level scan (parameterized n) ====================
__global__ void scan1_kernel(const u32* __restrict__ counts, u32* __restrict__ bsum, int n) {
    __shared__ u32 sd[256];
    int tid = threadIdx.x;
    int base = blockIdx.x * SCAN_ELEMS + tid * 16;
    u32 s = 0;
    #pragma unroll
    for (int j = 0; j < 16; j++) { int i = base + j; if (i < n) s += counts[i]; }
    sd[tid] = s; __syncthreads();
    for (int st = 128; st > 0; st >>= 1) { if (tid < st) sd[tid] += sd[tid + st]; __syncthreads(); }
    if (tid == 0) bsum[blockIdx.x] = sd[0];
}

__global__ void scan2_kernel(u32* __restrict__ bsum, u32* __restrict__ starts, int nb, int n) {
    __shared__ u32 sd[256];
    int tid = threadIdx.x;
    u32 v = (tid < nb) ? bsum[tid] : 0;
    sd[tid] = v; __syncthreads();
    for (int st = 1; st < 256; st <<= 1) {
        u32 t = (tid >= st) ? sd[tid - st] : 0;
        __syncthreads();
        sd[tid] += t;
        __syncthreads();
    }
    if (tid < nb) bsum[tid] = sd[tid] - v;     // exclusive
    if (tid == 255) starts[n] = sd[255];       // total
}

__global__ void scan3_kernel(const u32* __restrict__ counts, const u32* __restrict__ bsum,
                             u32* __restrict__ starts, int n) {
    __shared__ u32 sd[256];
    int tid = threadIdx.x;
    int base = blockIdx.x * SCAN_ELEMS + tid * 16;
    u32 v[16]; u32 s = 0;
    #pragma unroll
    for (int j = 0; j < 16; j++) { int i = base + j; v[j] = (i < n) ? counts[i] : 0; s += v[j]; }
    sd[tid] = s; __syncthreads();
    for (int st = 1; st < 256; st <<= 1) {
        u32 t = (tid >= st) ? sd[tid - st] : 0;
        __syncthreads();
        sd[tid] += t;
        __syncthreads();
    }
    u32 run = bsum[blockIdx.x] + sd[tid] - s;
    #pragma unroll
    for (int j = 0; j < 16; j++) { int i = base + j; if (i < n) starts[i] = run; run += v[j]; }
}

// kc layout (u32): cnt[0..63], start[64..64+nb], cursor[160..160+nb)
__global__ void scanKC_kernel(u32* __restrict__ kc, int nb) {
    if (threadIdx.x == 0 && blockIdx.x == 0) {
        u32 run = 0;
        for (int i = 0; i < nb; i++) { kc[64 + i] = run; kc[160 + i] = run; run += kc[i]; }
        kc[64 + nb] = run;
    }
}

// ==================== build per-(k,chunk) work lists ====================
__global__ void buildlists_kernel(const int* __restrict__ iidx, const int* __restrict__ oidx,
                                  const u32* __restrict__ rowstart, u32* __restrict__ cursorO,
                                  u32* __restrict__ kc /* cursor at +160 */,
                                  u32* __restrict__ listIn, u32* __restrict__ listDst,
                                  int C, int CH) {
    __shared__ u32 cnt[64], base[64];
    int tid = threadIdx.x;
    if (tid < 64) cnt[tid] = 0;
    __syncthreads();
    int p = blockIdx.x * 256 + tid;
    bool valid = p < NPAIRS;
    int bin = 0; u32 np = 0, my = 0;
    if (valid) {
        int o = oidx[p];
        int k = p / R_PAIRS;
        bin = k * C + o / CH;
        np = rowstart[o] + atomicAdd(&cursorO[o], 1u);
        my = atomicAdd(&cnt[bin], 1u);
    }
    __syncthreads();
    if (tid < 64 && cnt[tid]) base[tid] = atomicAdd(&kc[160 + tid], cnt[tid]);
    __syncthreads();
    if (valid) {
        u32 idx = base[bin] + my;
        listIn[idx]  = (u32)iidx[p];
        listDst[idx] = np;
    }
}

// ==================== conv1+conv2 phase A ====================
// grid (tiles, 8). wave w: 64-col slice wcol of the 256-wide temp row.
__global__ __launch_bounds__(256) void convA12_kernel(
    const bf16* __restrict__ x1, const float* __restrict__ W1, const float* __restrict__ W2,
    const u32* __restrict__ listIn, const u32* __restrict__ listDst,
    const u32* __restrict__ startKC, const u32* __restrict__ rowstart,
    bf16* __restrict__ temp, int chunk, int C, int CH)
{
    int k    = blockIdx.y;
    int tid  = threadIdx.x;
    int wave = tid >> 6, lane = tid & 63;

    int bin = k * C + chunk;
    u32 lo = startKC[bin], hi = startKC[bin + 1];
    u32 ntiles = (hi - lo + 63) >> 6;
    u32 t0 = blockIdx.x * ATILES;
    if (t0 >= ntiles) return;
    u32 chunk_base = rowstart[(long)chunk * CH];

    __shared__ bf16 As[64 * 64];
    __shared__ bf16 stage[4][64 * 64];
    __shared__ u32 s_dst[64];
    char* asb = (char*)As;
    char* stb = (char*)stage[wave];

    int l15 = lane & 15;
    int kr0 = (lane >> 4) * 8;
    const float* Wk = ((wave & 2) ? W2 : W1) + (long)k * CIN * COUT;
    int nbase = (wave & 1) * 64;
    int wcol  = nbase + ((wave & 2) ? 128 : 0);

    bf16x8 bfrag[2][4];
    #pragma unroll
    for (int ks = 0; ks < 2; ks++)
        #pragma unroll
        for (int nf = 0; nf < 4; nf++) {
            const float* p = Wk + (long)(ks * 32 + kr0) * COUT + nbase + nf * 16 + l15;
            bf16x8 b;
            #pragma unroll
            for (int j = 0; j < 8; j++) b[j] = (bf16)p[(long)j * COUT];
            bfrag[ks][nf] = b;
        }

    int grow = tid >> 2, gpart = tid & 3;
    int rbase = (lane >> 4) * 4;

    for (int t = 0; t < ATILES; t++) {
        u32 tile = t0 + t;
        if (tile >= ntiles) break;
        u32 pos0 = lo + tile * 64;

        if (tid < 64) {
            u32 p = pos0 + tid;
            s_dst[tid] = (p < hi) ? (listDst[p] - chunk_base) : 0xFFFFFFFFu;
        }
        {
            u32 p = pos0 + grow;
            u32 in = (p < hi) ? listIn[p] : 0u;
            const char* src = (const char*)(x1 + (long)in * CIN) + gpart * 32;
            int4 a = *(const int4*)src;
            int4 b = *(const int4*)(src + 16);
            int boff0 = (grow * 128 + gpart * 32)      ^ ((grow & 7) << 4);
            int boff1 = (grow * 128 + gpart * 32 + 16) ^ ((grow & 7) << 4);
            *(int4*)(asb + boff0) = a;
            *(int4*)(asb + boff1) = b;
        }
        __syncthreads();

        f32x4 acc[4][4];
        #pragma unroll
        for (int m = 0; m < 4; m++)
            #pragma unroll
            for (int n = 0; n < 4; n++) acc[m][n] = (f32x4)(0.f);

        #pragma unroll
        for (int ks = 0; ks < 2; ks++) {
            bf16x8 af[4];
            #pragma unroll
            for (int m = 0; m < 4; m++) {
                int row = m * 16 + l15;
                int boff = (row * 128 + (ks * 32 + kr0) * 2) ^ ((row & 7) << 4);
                af[m] = *(bf16x8*)(asb + boff);
            }
            #pragma unroll
            for (int m = 0; m < 4; m++)
                #pragma unroll
                for (int nf = 0; nf < 4; nf++)
                    acc[m][nf] = __builtin_amdgcn_mfma_f32_16x16x32_bf16(
                        af[m], bfrag[ks][nf], acc[m][nf], 0, 0, 0);
        }

        // ---- stage (per-wave, 64 rows x 64 cols) ----
        #pragma unroll
        for (int m = 0; m < 4; m++)
            #pragma unroll
            for (int nf = 0; nf < 4; nf++)
                #pragma unroll
                for (int j = 0; j < 4; j++) {
                    int r = m * 16 + rbase + j;
                    int col = nf * 16 + l15;
                    int soff = (r * 128 + col * 2) ^ (((r >> 2) & 7) << 4);
                    *(bf16*)(stb + soff) = (bf16)acc[m][nf][j];
                }
        // ---- coalesced scattered row stores: 8 rows x 128B per instr ----
        #pragma unroll
        for (int i = 0; i < 8; i++) {
            int r = i * 8 + (lane >> 3);
            u32 dst = s_dst[r];
            if (dst != 0xFFFFFFFFu) {
                int soff = (r * 128 + ((lane & 7) * 16)) ^ (((r >> 2) & 7) << 4);
                int4 v = *(int4*)(stb + soff);
                *(int4*)((char*)(temp + (size_t)dst * 256) + wcol * 2 + (lane & 7) * 16) = v;
            }
        }
        __syncthreads();
    }
}

// ==================== conv12 phase B: single segment per row ====================
__global__ __launch_bounds__(256) void convB12_kernel(
    const bf16* __restrict__ temp, const u32* __restrict__ rowstart,
    bf16* __restrict__ y1, float* __restrict__ out, float* __restrict__ sums2,
    int chunk, int CH)
{
    __shared__ float bnacc[256];
    int tid = threadIdx.x;
    bnacc[tid] = 0.f;
    __syncthreads();
    int lane = tid & 63;
    int wid = blockIdx.x * 4 + (tid >> 6);
    int nw  = gridDim.x * 4;
    u32 cb = rowstart[(long)chunk * CH];
    float bs[4] = {0,0,0,0}, bq[4] = {0,0,0,0};

    for (int ol = wid; ol < CH; ol += nw) {
        long o = (long)chunk * CH + ol;
        u32 rs = rowstart[o], re = rowstart[o + 1];
        float a[4] = {0,0,0,0};
        for (u32 pos = rs; pos < re; pos++) {
            bf16x4 v = *(const bf16x4*)(temp + (size_t)(pos - cb) * 256 + lane * 4);
            #pragma unroll
            for (int j = 0; j < 4; j++) a[j] += (float)v[j];
        }
        if (lane < 32) {
            bf16x4 h;
            #pragma unroll
            for (int j = 0; j < 4; j++) {
                h[j] = (bf16)a[j];
                bs[j] += a[j]; bq[j] += a[j] * a[j];
            }
            *(bf16x4*)(y1 + o * COUT + lane * 4) = h;
        } else {
            *(float4*)(out + o * COUT + (lane - 32) * 4) = make_float4(a[0], a[1], a[2], a[3]);
        }
    }
    if (lane < 32) {
        #pragma unroll
        for (int j = 0; j < 4; j++) {
            atomicAdd(&bnacc[lane * 4 + j], bs[j]);
            atomicAdd(&bnacc[128 + lane * 4 + j], bq[j]);
        }
    }
    __syncthreads();
    atomicAdd(&sums2[tid], bnacc[tid]);
}

// ==================== submanifold phase A (BN2+ReLU fused in gather) ============
// 2x2 wave split: wave (wr,wc): rows wr*32..+32, cols wc*64..+64
__global__ __launch_bounds__(256) void convAs_kernel(
    const bf16* __restrict__ y1, const float* __restrict__ Ws, const float* __restrict__ ss2,
    const u32* __restrict__ listIn, const u32* __restrict__ listDst,
    const u32* __restrict__ startKC, const u32* __restrict__ rowstart,
    bf16* __restrict__ temp, int chunk, int C, int CH)
{
    int k    = blockIdx.y;
    int tid  = threadIdx.x;
    int wave = tid >> 6, lane = tid & 63;
    int wr = wave >> 1, wc = wave & 1;

    int bin = k * C + chunk;
    u32 lo = startKC[bin], hi = startKC[bin + 1];
    u32 ntiles = (hi - lo + 63) >> 6;
    u32 t0 = blockIdx.x * ATILES;
    if (t0 >= ntiles) return;
    u32 chunk_base = rowstart[(long)chunk * CH];

    __shared__ bf16 As[64 * 128];
    __shared__ bf16 stage[4][32 * 64];
    __shared__ u32 s_dst[64];
    __shared__ float s_sc[128], s_sh[128];
    char* asb = (char*)As;
    char* stb = (char*)stage[wave];

    if (tid < 128) { s_sc[tid] = ss2[tid]; s_sh[tid] = ss2[128 + tid]; }

    int l15 = lane & 15;
    int kr0 = (lane >> 4) * 8;
    const float* Wk = Ws + (long)k * COUT * COUT;
    int nbase = wc * 64;
    int mbase = wr * 32;

    bf16x8 bfrag[4][4];
    #pragma unroll
    for (int ks = 0; ks < 4; ks++)
        #pragma unroll
        for (int nf = 0; nf < 4; nf++) {
            const float* p = Wk + (long)(ks * 32 + kr0) * COUT + nbase + nf * 16 + l15;
            bf16x8 b;
            #pragma unroll
            for (int j = 0; j < 8; j++) b[j] = (bf16)p[(long)j * COUT];
            bfrag[ks][nf] = b;
        }

    int grow = tid >> 2, gpart = tid & 3;
    int rbase = (lane >> 4) * 4;

    __syncthreads();   // s_sc/s_sh ready

    for (int t = 0; t < ATILES; t++) {
        u32 tile = t0 + t;
        if (tile >= ntiles) break;
        u32 pos0 = lo + tile * 64;

        if (tid < 64) {
            u32 p = pos0 + tid;
            s_dst[tid] = (p < hi) ? (listDst[p] - chunk_base) : 0xFFFFFFFFu;
        }
        {
            u32 p = pos0 + grow;
            u32 in = (p < hi) ? listIn[p] : 0u;
            const bf16* src = y1 + (long)in * COUT + gpart * 32;
            #pragma unroll
            for (int q = 0; q < 4; q++) {
                bf16x8 v = *(const bf16x8*)(src + q * 8);
                int c0 = gpart * 32 + q * 8;
                bf16x8 h;
                #pragma unroll
                for (int j = 0; j < 8; j++)
                    h[j] = (bf16)fmaxf((float)v[j] * s_sc[c0 + j] + s_sh[c0 + j], 0.f);
                int boff = (grow * 256 + c0 * 2) ^ ((grow & 7) << 4);
                *(bf16x8*)(asb + boff) = h;
            }
        }
        __syncthreads();

        f32x4 acc[2][4];
        #pragma unroll
        for (int m = 0; m < 2; m++)
            #pragma unroll
            for (int n = 0; n < 4; n++) acc[m][n] = (f32x4)(0.f);

        #pragma unroll
        for (int ks = 0; ks < 4; ks++) {
            bf16x8 af[2];
            #pragma unroll
            for (int m = 0; m < 2; m++) {
                int row = mbase + m * 16 + l15;
                int boff = (row * 256 + (ks * 32 + kr0) * 2) ^ ((row & 7) << 4);
                af[m] = *(bf16x8*)(asb + boff);
            }
            #pragma unroll
            for (int m = 0; m < 2; m++)
                #pragma unroll
                for (int nf = 0; nf < 4; nf++)
                    acc[m][nf] = __builtin_amdgcn_mfma_f32_16x16x32_bf16(
                        af[m], bfrag[ks][nf], acc[m][nf], 0, 0, 0);
        }

        // ---- stage (per-wave, 32 rows x 64 cols) ----
        #pragma unroll
        for (int m = 0; m < 2; m++)
            #pragma unroll
            for (int nf = 0; nf < 4; nf++)
                #pragma unroll
                for (int j = 0; j < 4; j++) {
                    int r = m * 16 + rbase + j;
                    int col = nf * 16 + l15;
                    int soff = (r * 128 + col * 2) ^ (((r >> 2) & 7) << 4);
                    *(bf16*)(stb + soff) = (bf16)acc[m][nf][j];
                }
        // ---- stores: 8 rows x 128B per instr, 4 iters for 32 rows ----
        #pragma unroll
        for (int i = 0; i < 4; i++) {
            int r = i * 8 + (lane >> 3);
            u32 dst = s_dst[mbase + r];
            if (dst != 0xFFFFFFFFu) {
                int soff = (r * 128 + ((lane & 7) * 16)) ^ (((r >> 2) & 7) << 4);
                int4 v = *(int4*)(stb + soff);
                *(int4*)((char*)(temp + (size_t)dst * 128) + nbase * 2 + (lane & 7) * 16) = v;
            }
        }
        __syncthreads();
    }
}

// ==================== submanifold phase B: RMW into out ====================
__global__ __launch_bounds__(256) void convBs_kernel(
    const bf16* __restrict__ temp, const u32* __restrict__ rowstart,
    float* __restrict__ out, int chunk, int CH)
{
    int tid = threadIdx.x, lane = tid & 63;
    int wid = blockIdx.x * 4 + (tid >> 6);
    int nw  = gridDim.x * 4;
    u32 cb = rowstart[(long)chunk * CH];

    for (int ol = wid; ol < CH; ol += nw) {
        long o = (long)chunk * CH + ol;
        u32 rs = rowstart[o], re = rowstart[o + 1];
        float a0 = 0.f, a1 = 0.f;
        for (u32 pos = rs; pos < re; pos++) {
            bf16x2 v = *(const bf16x2*)(temp + (size_t)(pos - cb) * 128 + lane * 2);
            a0 += (float)v[0]; a1 += (float)v[1];
        }
        float2* po = (float2*)(out + o * COUT + lane * 2);
        float2 v = *po; v.x += a0; v.y += a1; *po = v;
    }
}

// ==================== fallback (round-1 atomic path) ====================
__global__ __launch_bounds__(256) void conv12_atomic_kernel(
    const float* __restrict__ x,
    const float* __restrict__ W1, const float* __restrict__ W2,
    const int* __restrict__ in_idx, const int* __restrict__ out_idx,
    const float* __restrict__ ss1,
    float* __restrict__ y1, float* __restrict__ y2)
{
    int k    = blockIdx.y;
    int tid  = threadIdx.x;
    int wave = tid >> 6, lane = tid & 63;

    __shared__ bf16 As[64 * 64];
    __shared__ int  s_out[64];
    __shared__ float s_sc[64], s_sh[64];
    char* asb = (char*)As;

    if (tid < 64) { s_sc[tid] = ss1[tid]; s_sh[tid] = ss1[64 + tid]; }

    const float* Wk = ((wave & 2) ? W2 : W1) + (long)k * CIN * COUT;
    int nbase = (wave & 1) * 64;
    int l15 = lane & 15;
    int kr0 = (lane >> 4) * 8;

    bf16x8 bfrag[2][4];
    #pragma unroll
    for (int ks = 0; ks < 2; ks++)
        #pragma unroll
        for (int nf = 0; nf < 4; nf++) {
            const float* p = Wk + (long)(ks * 32 + kr0) * COUT + nbase + nf * 16 + l15;
            bf16x8 b;
            #pragma unroll
            for (int j = 0; j < 8; j++) b[j] = (bf16)p[(long)j * COUT];
            bfrag[ks][nf] = b;
        }

    const int* in_k  = in_idx  + k * R_PAIRS;
    const int* out_k = out_idx + k * R_PAIRS;
    float* ybase = (wave & 2) ? y2 : y1;

    int grow = tid >> 2;
    int gcol = (tid & 3) * 16;

    __syncthreads();

    for (int t = 0; t < OLD_TILES; t++) {
        int pair0 = blockIdx.x * (OLD_TILES * 64) + t * 64;
        {
            int p = pair0 + grow;
            bool valid = p < R_PAIRS;
            long src = valid ? (long)in_k[p] : 0;
            const float4* xr = (const float4*)(x + src * CIN + gcol);
            #pragma unroll
            for (int g = 0; g < 2; g++) {
                float4 va = make_float4(0, 0, 0, 0), vb = va;
                if (valid) { va = xr[g * 2]; vb = xr[g * 2 + 1]; }
                float f[8] = {va.x, va.y, va.z, va.w, vb.x, vb.y, vb.z, vb.w};
                bf16x8 h;
                #pragma unroll
                for (int j = 0; j < 8; j++) {
                    int c = gcol + g * 8 + j;
                    h[j] = (bf16)fmaxf(f[j] * s_sc[c] + s_sh[c], 0.f);
                }
                int boff = ((grow * 128) + (gcol + g * 8) * 2) ^ ((grow & 7) << 4);
                *(bf16x8*)(asb + boff) = h;
            }
        }
        if (tid < 64) {
            int p = pair0 + tid;
            s_out[tid] = (p < R_PAIRS) ? out_k[p] : -1;
        }
        __syncthreads();

        f32x4 acc[4][4];
        #pragma unroll
        for (int m = 0; m < 4; m++)
            #pragma unroll
            for (int n = 0; n < 4; n++) acc[m][n] = (f32x4)(0.f);

        #pragma unroll
        for (int ks = 0; ks < 2; ks++) {
            bf16x8 af[4];
            #pragma unroll
            for (int m = 0; m < 4; m++) {
                int row = m * 16 + l15;
                int boff = (row * 128 + (ks * 32 + kr0) * 2) ^ ((row & 7) << 4);
                af[m] = *(bf16x8*)(asb + boff);
            }
            #pragma unroll
            for (int m = 0; m < 4; m++)
                #pragma unroll
                for (int nf = 0; nf < 4; nf++)
                    acc[m][nf] = __builtin_amdgcn_mfma_f32_16x16x32_bf16(
                        af[m], bfrag[ks][nf], acc[m][nf], 0, 0, 0);
        }

        int rbase = (lane >> 4) * 4;
        #pragma unroll
        for (int m = 0; m < 4; m++)
            #pragma unroll
            for (int j = 0; j < 4; j++) {
                int o = s_out[m * 16 + rbase + j];
                if (o >= 0)
                    #pragma unroll
                    for (int nf = 0; nf < 4; nf++)
                        atomicAdd(&ybase[(long)o * COUT + nbase + nf * 16 + l15],
                                  acc[m][nf][j]);
            }
        __syncthreads();
    }
}

__global__ __launch_bounds__(256) void convs_atomic_kernel(
    const float* __restrict__ y1,
    const float* __restrict__ Ws,
    const int* __restrict__ in_idx, const int* __restrict__ out_idx,
    const float* __restrict__ ss2,
    float* __restrict__ out)
{
    int k    = blockIdx.y;
    int tid  = threadIdx.x;
    int wave = tid >> 6, lane = tid & 63;

    __shared__ bf16 As[64 * 128];
    __shared__ int  s_out[64];
    __shared__ float s_sc[128], s_sh[128];
    char* asb = (char*)As;

    if (tid < 128) { s_sc[tid] = ss2[tid]; s_sh[tid] = ss2[128 + tid]; }

    const float* Wk = Ws + (long)k * COUT * COUT;
    int nbase = wave * 32;
    int l15 = lane & 15;
    int kr0 = (lane >> 4) * 8;

    bf16x8 bfrag[4][2];
    #pragma unroll
    for (int ks = 0; ks < 4; ks++)
        #pragma unroll
        for (int nf = 0; nf < 2; nf++) {
            const float* p = Wk + (long)(ks * 32 + kr0) * COUT + nbase + nf * 16 + l15;
            bf16x8 b;
            #pragma unroll
            for (int j = 0; j < 8; j++) b[j] = (bf16)p[(long)j * COUT];
            bfrag[ks][nf] = b;
        }

    const int* in_k  = in_idx  + k * R_PAIRS;
    const int* out_k = out_idx + k * R_PAIRS;

    int grow = tid >> 2;
    int gcol = (tid & 3) * 32;

    __syncthreads();

    for (int t = 0; t < OLD_TILES; t++) {
        int pair0 = blockIdx.x * (OLD_TILES * 64) + t * 64;
        {
            int p = pair0 + grow;
            bool valid = p < R_PAIRS;
            long src = valid ? (long)in_k[p] : 0;
            const float4* yr = (const float4*)(y1 + src * COUT + gcol);
            #pragma unroll
            for (int g = 0; g < 4; g++) {
                float4 va = make_float4(0, 0, 0, 0), vb = va;
                if (valid) { va = yr[g * 2]; vb = yr[g * 2 + 1]; }
                float f[8] = {va.x, va.y, va.z, va.w, vb.x, vb.y, vb.z, vb.w};
                bf16x8 h;
                #pragma unroll
                for (int j = 0; j < 8; j++) {
                    int c = gcol + g * 8 + j;
                    h[j] = (bf16)fmaxf(f[j] * s_sc[c] + s_sh[c], 0.f);
                }
                int boff = (grow * 256 + (gcol + g * 8) * 2) ^ ((grow & 7) << 4);
                *(bf16x8*)(asb + boff) = h;
            }
        }
        if (tid < 64) {
            int p = pair0 + tid;
            s_out[tid] = (p < R_PAIRS) ? out_k[p] : -1;
        }
        __syncthreads();

        f32x4 acc[4][2];
        #pragma unroll
        for (int m = 0; m < 4; m++)
            #pragma unroll
            for (int n = 0; n < 2; n++) acc[m][n] = (f32x4)(0.f);

        #pragma unroll
        for (int ks = 0; ks < 4; ks++) {
            bf16x8 af[4];
            #pragma unroll
            for (int m = 0; m < 4; m++) {
                int row = m * 16 + l15;
                int boff = (row * 256 + (ks * 32 + kr0) * 2) ^ ((row & 7) << 4);
                af[m] = *(bf16x8*)(asb + boff);
            }
            #pragma unroll
            for (int m = 0; m < 4; m++)
                #pragma unroll
                for (int nf = 0; nf < 2; nf++)
                    acc[m][nf] = __builtin_amdgcn_mfma_f32_16x16x32_bf16(
                        af[m], bfrag[ks][nf], acc[m][nf], 0, 0, 0);
        }

        int rbase = (lane >> 4) * 4;
        #pragma unroll
        for (int m = 0; m < 4; m++)
            #pragma unroll
            for (int j = 0; j < 4; j++) {
                int o = s_out[m * 16 + rbase + j];
                if (o >= 0)
                    #pragma unroll
                    for (int nf = 0; nf < 2; nf++)
                        atomicAdd(&out[(long)o * COUT + nbase + nf * 16 + l15],
                                  acc[m][nf][j]);
            }
        __syncthreads();
    }
}

// ==================== host ====================
extern "C" void kernel_launch(void* const* d_in, const int* in_sizes, int n_in,
                              void* d_out, int out_size, void* d_ws, size_t ws_size,
                              hipStream_t stream) {
    const float* x       = (const float*)d_in[0];
    const float* gamma1  = (const float*)d_in[1];
    const float* beta1   = (const float*)d_in[2];
    const float* gamma2  = (const float*)d_in[3];
    const float* beta2   = (const float*)d_in[4];
    const float* W1      = (const float*)d_in[5];
    const float* Ws      = (const float*)d_in[6];
    const float* W2      = (const float*)d_in[7];
    const int*   in_idx1   = (const int*)d_in[8];
    const int*   out_idx1  = (const int*)d_in[9];
    const int*   in_idx_s  = (const int*)d_in[10];
    const int*   out_idx_s = (const int*)d_in[11];

    float* out = (float*)d_out;
    char*  ws  = (char*)d_ws;

    auto a256 = [](size_t v) { return (v + 255) & ~(size_t)255; };

    size_t off_y1      = 0;                                    // bf16 y1: 32 MB
    size_t off_sums    = a256(off_y1 + 32000000);              // 4 KB stats
    size_t off_x1      = a256(off_sums + 4096);                // bf16 x1: 64 MB
    size_t off_countO  = a256(off_x1 + 64000000);              // 500 KB
    size_t off_cursorO = a256(off_countO + 4 * N_OUT);         // 500 KB
    size_t off_rows    = a256(off_cursorO + 4 * N_OUT);        // rowstart: 500 KB
    size_t off_bsum    = a256(off_rows + 4 * (N_OUT + 1));     // 1 KB
    size_t off_kc      = a256(off_bsum + 1024);                // 1 KB
    size_t off_listIn  = a256(off_kc + 1024);                  // 2 MB
    size_t off_listDst = a256(off_listIn + 4 * NPAIRS);        // 2 MB
    size_t off_temp    = a256(off_listDst + 4 * NPAIRS);

    int C = 0;
    const int cands[3] = {2, 4, 8};
    for (int ci = 0; ci < 3; ci++) {
        size_t cap = (size_t)(NPAIRS / cands[ci]) + 8192;
        if (off_temp + cap * 512 <= ws_size) { C = cands[ci]; break; }
    }

    if (C == 0) {
        // -------- fallback: atomic path (needs only 64 MB + 4 KB) --------
        float* y1f   = (float*)ws;
        float* stats = y1f + (long)N_OUT * COUT;
        float* sums1 = stats;
        float* ss1   = stats + 128;
        float* sums2 = stats + 256;
        float* ss2   = stats + 512;

        hipMemsetAsync(d_out, 0, (size_t)N_OUT * COUT * 4, stream);
        hipMemsetAsync(d_ws,  0, (size_t)N_OUT * COUT * 4 + 768 * 4, stream);

        bn_stats_kernel<64><<<1024, 256, 0, stream>>>(x, N_IN, sums1);
        bn_finalize_kernel<64><<<1, 64, 0, stream>>>(sums1, gamma1, beta1, 1.f / N_IN, ss1);

        dim3 cgrid((R_PAIRS + OLD_TILES * 64 - 1) / (OLD_TILES * 64), K_OFF);
        conv12_atomic_kernel<<<cgrid, 256, 0, stream>>>(x, W1, W2, in_idx1, out_idx1, ss1, y1f, out);

        bn_stats_kernel<128><<<1024, 256, 0, stream>>>(y1f, N_OUT, sums2);
        bn_finalize_kernel<128><<<1, 128, 0, stream>>>(sums2, gamma2, beta2, 1.f / N_OUT, ss2);

        convs_atomic_kernel<<<cgrid, 256, 0, stream>>>(y1f, Ws, in_idx_s, out_idx_s, ss2, out);
        return;
    }

    int CH = N_OUT / C;

    bf16*  y1      = (bf16*)(ws + off_y1);
    float* sums1   = (float*)(ws + off_sums);     // [256]
    float* ss1     = sums1 + 256;                 // [128+pad: 256]
    float* sums2   = sums1 + 512;                 // [256]
    float* ss2     = sums1 + 768;                 // [256]
    bf16*  x1      = (bf16*)(ws + off_x1);
    u32*   countO  = (u32*)(ws + off_countO);
    u32*   cursorO = (u32*)(ws + off_cursorO);
    u32*   rows    = (u32*)(ws + off_rows);
    u32*   bsum    = (u32*)(ws + off_bsum);
    u32*   kc      = (u32*)(ws + off_kc);         // cnt[0..63], start[64..], cursor[160..]
    u32*   listIn  = (u32*)(ws + off_listIn);
    u32*   listDst = (u32*)(ws + off_listDst);
    bf16*  temp    = (bf16*)(ws + off_temp);

    int nbKC = K_OFF * C;
    int maxseg = R_PAIRS / C + 2048;
    int tilesA = ((maxseg + 63) / 64 + ATILES - 1) / ATILES;
    dim3 gA(tilesA, K_OFF);

    // ---- BN1 stats + apply -> x1 (bf16) ----
    hipMemsetAsync(sums1, 0, 4096, stream);
    bn_stats_kernel<64><<<1024, 256, 0, stream>>>(x, N_IN, sums1);
    bn_finalize_kernel<64><<<1, 64, 0, stream>>>(sums1, gamma1, beta1, 1.f / N_IN, ss1);
    bn_apply_f32_kernel<64><<<4096, 256, 0, stream>>>(x, ss1, x1, (long)N_IN * CIN / 8);

    // ---- rulebook 1: out-major sort + (k,chunk) lists ----
    hipMemsetAsync(countO, 0, 4 * N_OUT, stream);
    hipMemsetAsync(kc, 0, 1024, stream);
    histO_kernel<<<512, 256, 0, stream>>>(out_idx1, countO, kc, C, CH);
    scan1_kernel<<<NSB_OUT, 256, 0, stream>>>(countO, bsum, N_OUT);
    scan2_kernel<<<1, 256, 0, stream>>>(bsum, rows, NSB_OUT, N_OUT);
    scan3_kernel<<<NSB_OUT, 256, 0, stream>>>(countO, bsum, rows, N_OUT);
    scanKC_kernel<<<1, 1, 0, stream>>>(kc, nbKC);
    hipMemsetAsync(cursorO, 0, 4 * N_OUT, stream);
    buildlists_kernel<<<(NPAIRS + 255) / 256, 256, 0, stream>>>(
        in_idx1, out_idx1, rows, cursorO, kc, listIn, listDst, C, CH);

    // ---- conv1+conv2 per chunk ----
    for (int c = 0; c < C; c++) {
        convA12_kernel<<<gA, 256, 0, stream>>>(x1, W1, W2, listIn, listDst,
                                               kc + 64, rows, temp, c, C, CH);
        convB12_kernel<<<4096, 256, 0, stream>>>(temp, rows, y1, out, sums2, c, CH);
    }

    // ---- BN2 finalize (stats fused into convB12) ----
    bn_finalize_kernel<128><<<1, 128, 0, stream>>>(sums2, gamma2, beta2, 1.f / N_OUT, ss2);

    // ---- rulebook s: out-major sort + lists (reuse buffers) ----
    hipMemsetAsync(countO, 0, 4 * N_OUT, stream);
    hipMemsetAsync(kc, 0, 1024, stream);
    histO_kernel<<<512, 256, 0, stream>>>(out_idx_s, countO, kc, C, CH);
    scan1_kernel<<<NSB_OUT, 256, 0, stream>>>(countO, bsum, N_OUT);
    scan2_kernel<<<1, 256, 0, stream>>>(bsum, rows, NSB_OUT, N_OUT);
    scan3_kernel<<<NSB_OUT, 256, 0, stream>>>(countO, bsum, rows, N_OUT);
    scanKC_kernel<<<1, 1, 0, stream>>>(kc, nbKC);
    hipMemsetAsync(cursorO, 0, 4 * N_OUT, stream);
    buildlists_kernel<<<(NPAIRS + 255) / 256, 256, 0, stream>>>(
        in_idx_s, out_idx_s, rows, cursorO, kc, listIn, listDst, C, CH);

    // ---- submanifold conv per chunk (BN2+ReLU fused into gather) ----
    for (int c = 0; c < C; c++) {
        convAs_kernel<<<gA, 256, 0, stream>>>(y1, Ws, ss2, listIn, listDst,
                                              kc + 64, rows, temp, c, C, CH);
        convBs_kernel<<<4096, 256, 0, stream>>>(temp, rows, out, c, CH);
    }
}

// Round 6
// 574.404 us; speedup vs baseline: 1.2650x; 1.2650x over previous
//
#include <hip/hip_runtime.h>

#define K_OFF   8
#define R_PAIRS 62500
#define NPAIRS  500000
#define N_IN    500000
#define N_OUT   125000
#define CIN     64
#define COUT    128
#define BN_EPS  1e-4f
#define SCAN_ELEMS 4096
#define NSB_OUT 31           // ceil(N_OUT / 4096)
#define ATILES  2
#define OLD_TILES 8

typedef __bf16 bf16;
typedef __bf16 bf16x2 __attribute__((ext_vector_type(2)));
typedef __bf16 bf16x4 __attribute__((ext_vector_type(4)));
typedef __bf16 bf16x8 __attribute__((ext_vector_type(8)));
typedef float  f32x4  __attribute__((ext_vector_type(4)));
typedef unsigned int u32;

// ==================== BN statistics ====================
template<int C>
__global__ void bn_stats_kernel(const float* __restrict__ x, int n_rows,
                                float* __restrict__ sums /* [2C] */) {
    constexpr int CG = C / 4;
    int tid = blockIdx.x * blockDim.x + threadIdx.x;
    int nth = gridDim.x * blockDim.x;
    const float4* x4 = (const float4*)x;
    long n4 = (long)n_rows * CG;
    int cg = tid % CG;
    float s[4] = {0,0,0,0}, q[4] = {0,0,0,0};
    for (long i = tid; i < n4; i += nth) {
        float4 v = x4[i];
        float f[4] = {v.x, v.y, v.z, v.w};
        #pragma unroll
        for (int j = 0; j < 4; j++) { s[j] += f[j]; q[j] += f[j] * f[j]; }
    }
    __shared__ float acc[2 * C];
    for (int i = threadIdx.x; i < 2 * C; i += blockDim.x) acc[i] = 0.f;
    __syncthreads();
    #pragma unroll
    for (int j = 0; j < 4; j++) {
        atomicAdd(&acc[cg * 4 + j], s[j]);
        atomicAdd(&acc[C + cg * 4 + j], q[j]);
    }
    __syncthreads();
    for (int i = threadIdx.x; i < 2 * C; i += blockDim.x) atomicAdd(&sums[i], acc[i]);
}

template<int C>
__global__ void bn_finalize_kernel(const float* __restrict__ sums,
                                   const float* __restrict__ gamma,
                                   const float* __restrict__ beta,
                                   float inv_n, float* __restrict__ ss) {
    int c = threadIdx.x;
    if (c < C) {
        float m  = sums[c] * inv_n;
        float v  = sums[C + c] * inv_n - m * m;
        float sc = gamma[c] * rsqrtf(v + BN_EPS);
        ss[c]     = sc;
        ss[C + c] = beta[c] - m * sc;
    }
}

// ==================== BN apply + ReLU -> bf16 (fp32 in) ====================
template<int C>
__global__ void bn_apply_f32_kernel(const float* __restrict__ x, const float* __restrict__ ss,
                                    bf16* __restrict__ xo, long items /* rows*C/8 */) {
    constexpr int CG = C / 8;
    long i = (long)blockIdx.x * blockDim.x + threadIdx.x;
    long stride = (long)gridDim.x * blockDim.x;   // multiple of CG
    int cg = (int)(i % CG);
    float sc[8], sh[8];
    #pragma unroll
    for (int j = 0; j < 8; j++) { sc[j] = ss[cg*8+j]; sh[j] = ss[C + cg*8+j]; }
    for (; i < items; i += stride) {
        const float4* p = (const float4*)(x + i * 8);
        float4 a = p[0], b = p[1];
        float f[8] = {a.x,a.y,a.z,a.w,b.x,b.y,b.z,b.w};
        bf16x8 h;
        #pragma unroll
        for (int j = 0; j < 8; j++) h[j] = (bf16)fmaxf(f[j]*sc[j] + sh[j], 0.f);
        *(bf16x8*)(xo + i * 8) = h;
    }
}

// ==================== hist over out + (k,chunk) counts ====================
__global__ void histO_kernel(const int* __restrict__ oidx, u32* __restrict__ countO,
                             u32* __restrict__ kc /* cnt at +0 */, int C, int CH) {
    __shared__ u32 lc[64];
    int tid = threadIdx.x;
    if (tid < 64) lc[tid] = 0;
    __syncthreads();
    int p = blockIdx.x * blockDim.x + tid;
    int stride = gridDim.x * blockDim.x;
    for (; p < NPAIRS; p += stride) {
        int o = oidx[p];
        atomicAdd(&countO[o], 1u);
        atomicAdd(&lc[(p / R_PAIRS) * C + o / CH], 1u);
    }
    __syncthreads();
    if (tid < 64 && lc[tid]) atomicAdd(&kc[tid], lc[tid]);
}

// ==================== 3-level scan (parameterized n) ====================
__global__ void scan1_kernel(const u32* __restrict__ counts, u32* __restrict__ bsum, int n) {
    __shared__ u32 sd[256];
    int tid = threadIdx.x;
    int base = blockIdx.x * SCAN_ELEMS + tid * 16;
    u32 s = 0;
    #pragma unroll
    for (int j = 0; j < 16; j++) { int i = base + j; if (i < n) s += counts[i]; }
    sd[tid] = s; __syncthreads();
    for (int st = 128; st > 0; st >>= 1) { if (tid < st) sd[tid] += sd[tid + st]; __syncthreads(); }
    if (tid == 0) bsum[blockIdx.x] = sd[0];
}

__global__ void scan2_kernel(u32* __restrict__ bsum, u32* __restrict__ starts, int nb, int n) {
    __shared__ u32 sd[256];
    int tid = threadIdx.x;
    u32 v = (tid < nb) ? bsum[tid] : 0;
    sd[tid] = v; __syncthreads();
    for (int st = 1; st < 256; st <<= 1) {
        u32 t = (tid >= st) ? sd[tid - st] : 0;
        __syncthreads();
        sd[tid] += t;
        __syncthreads();
    }
    if (tid < nb) bsum[tid] = sd[tid] - v;     // exclusive
    if (tid == 255) starts[n] = sd[255];       // total
}

__global__ void scan3_kernel(const u32* __restrict__ counts, const u32* __restrict__ bsum,
                             u32* __restrict__ starts, int n) {
    __shared__ u32 sd[256];
    int tid = threadIdx.x;
    int base = blockIdx.x * SCAN_ELEMS + tid * 16;
    u32 v[16]; u32 s = 0;
    #pragma unroll
    for (int j = 0; j < 16; j++) { int i = base + j; v[j] = (i < n) ? counts[i] : 0; s += v[j]; }
    sd[tid] = s; __syncthreads();
    for (int st = 1; st < 256; st <<= 1) {
        u32 t = (tid >= st) ? sd[tid - st] : 0;
        __syncthreads();
        sd[tid] += t;
        __syncthreads();
    }
    u32 run = bsum[blockIdx.x] + sd[tid] - s;
    #pragma unroll
    for (int j = 0; j < 16; j++) { int i = base + j; if (i < n) starts[i] = run; run += v[j]; }
}

// kc layout (u32): cnt[0..63], start[64..64+nb], cursor[160..160+nb)
__global__ void scanKC_kernel(u32* __restrict__ kc, int nb) {
    if (threadIdx.x == 0 && blockIdx.x == 0) {
        u32 run = 0;
        for (int i = 0; i < nb; i++) { kc[64 + i] = run; kc[160 + i] = run; run += kc[i]; }
        kc[64 + nb] = run;
    }
}

// ==================== build per-(k,chunk) work lists ====================
__global__ void buildlists_kernel(const int* __restrict__ iidx, const int* __restrict__ oidx,
                                  const u32* __restrict__ rowstart, u32* __restrict__ cursorO,
                                  u32* __restrict__ kc /* cursor at +160 */,
                                  u32* __restrict__ listIn, u32* __restrict__ listDst,
                                  int C, int CH) {
    __shared__ u32 cnt[64], base[64];
    int tid = threadIdx.x;
    if (tid < 64) cnt[tid] = 0;
    __syncthreads();
    int p = blockIdx.x * 256 + tid;
    bool valid = p < NPAIRS;
    int bin = 0; u32 np = 0, my = 0;
    if (valid) {
        int o = oidx[p];
        int k = p / R_PAIRS;
        bin = k * C + o / CH;
        np = rowstart[o] + atomicAdd(&cursorO[o], 1u);
        my = atomicAdd(&cnt[bin], 1u);
    }
    __syncthreads();
    if (tid < 64 && cnt[tid]) base[tid] = atomicAdd(&kc[160 + tid], cnt[tid]);
    __syncthreads();
    if (valid) {
        u32 idx = base[bin] + my;
        listIn[idx]  = (u32)iidx[p];
        listDst[idx] = np;
    }
}

// ==================== conv1+conv2 phase A ====================
// grid (tiles, 8). wave w: 64-col slice wcol of the 256-wide temp row.
__global__ __launch_bounds__(256) void convA12_kernel(
    const bf16* __restrict__ x1, const float* __restrict__ W1, const float* __restrict__ W2,
    const u32* __restrict__ listIn, const u32* __restrict__ listDst,
    const u32* __restrict__ startKC, const u32* __restrict__ rowstart,
    bf16* __restrict__ temp, int chunk, int C, int CH)
{
    int k    = blockIdx.y;
    int tid  = threadIdx.x;
    int wave = tid >> 6, lane = tid & 63;

    int bin = k * C + chunk;
    u32 lo = startKC[bin], hi = startKC[bin + 1];
    u32 ntiles = (hi - lo + 63) >> 6;
    u32 t0 = blockIdx.x * ATILES;
    if (t0 >= ntiles) return;
    u32 chunk_base = rowstart[(long)chunk * CH];

    __shared__ bf16 As[64 * 64];
    __shared__ bf16 stage[4][64 * 64];
    __shared__ u32 s_dst[64];
    char* asb = (char*)As;
    char* stb = (char*)stage[wave];

    int l15 = lane & 15;
    int kr0 = (lane >> 4) * 8;
    const float* Wk = ((wave & 2) ? W2 : W1) + (long)k * CIN * COUT;
    int nbase = (wave & 1) * 64;
    int wcol  = nbase + ((wave & 2) ? 128 : 0);

    bf16x8 bfrag[2][4];
    #pragma unroll
    for (int ks = 0; ks < 2; ks++)
        #pragma unroll
        for (int nf = 0; nf < 4; nf++) {
            const float* p = Wk + (long)(ks * 32 + kr0) * COUT + nbase + nf * 16 + l15;
            bf16x8 b;
            #pragma unroll
            for (int j = 0; j < 8; j++) b[j] = (bf16)p[(long)j * COUT];
            bfrag[ks][nf] = b;
        }

    int grow = tid >> 2, gpart = tid & 3;
    int rbase = (lane >> 4) * 4;

    for (int t = 0; t < ATILES; t++) {
        u32 tile = t0 + t;
        if (tile >= ntiles) break;
        u32 pos0 = lo + tile * 64;

        if (tid < 64) {
            u32 p = pos0 + tid;
            s_dst[tid] = (p < hi) ? (listDst[p] - chunk_base) : 0xFFFFFFFFu;
        }
        {
            u32 p = pos0 + grow;
            u32 in = (p < hi) ? listIn[p] : 0u;
            const char* src = (const char*)(x1 + (long)in * CIN) + gpart * 32;
            int4 a = *(const int4*)src;
            int4 b = *(const int4*)(src + 16);
            int boff0 = (grow * 128 + gpart * 32)      ^ ((grow & 7) << 4);
            int boff1 = (grow * 128 + gpart * 32 + 16) ^ ((grow & 7) << 4);
            *(int4*)(asb + boff0) = a;
            *(int4*)(asb + boff1) = b;
        }
        __syncthreads();

        f32x4 acc[4][4];
        #pragma unroll
        for (int m = 0; m < 4; m++)
            #pragma unroll
            for (int n = 0; n < 4; n++) acc[m][n] = (f32x4)(0.f);

        #pragma unroll
        for (int ks = 0; ks < 2; ks++) {
            bf16x8 af[4];
            #pragma unroll
            for (int m = 0; m < 4; m++) {
                int row = m * 16 + l15;
                int boff = (row * 128 + (ks * 32 + kr0) * 2) ^ ((row & 7) << 4);
                af[m] = *(bf16x8*)(asb + boff);
            }
            #pragma unroll
            for (int m = 0; m < 4; m++)
                #pragma unroll
                for (int nf = 0; nf < 4; nf++)
                    acc[m][nf] = __builtin_amdgcn_mfma_f32_16x16x32_bf16(
                        af[m], bfrag[ks][nf], acc[m][nf], 0, 0, 0);
        }

        // ---- stage (per-wave, 64 rows x 64 cols) ----
        #pragma unroll
        for (int m = 0; m < 4; m++)
            #pragma unroll
            for (int nf = 0; nf < 4; nf++)
                #pragma unroll
                for (int j = 0; j < 4; j++) {
                    int r = m * 16 + rbase + j;
                    int col = nf * 16 + l15;
                    int soff = (r * 128 + col * 2) ^ (((r >> 2) & 7) << 4);
                    *(bf16*)(stb + soff) = (bf16)acc[m][nf][j];
                }
        // ---- coalesced scattered row stores: 8 rows x 128B per instr ----
        #pragma unroll
        for (int i = 0; i < 8; i++) {
            int r = i * 8 + (lane >> 3);
            u32 dst = s_dst[r];
            if (dst != 0xFFFFFFFFu) {
                int soff = (r * 128 + ((lane & 7) * 16)) ^ (((r >> 2) & 7) << 4);
                int4 v = *(int4*)(stb + soff);
                *(int4*)((char*)(temp + (size_t)dst * 256) + wcol * 2 + (lane & 7) * 16) = v;
            }
        }
        __syncthreads();
    }
}

// ==================== conv12 phase B: half-wave per row, MLP x4 ====================
// lane<32: row pair[0], lane>=32: row pair[1] (adjacent rows -> contiguous temp span).
// l32 0-15 -> y1 channels (bf16), l32 16-31 -> y2b channels (bf16).
__global__ __launch_bounds__(256) void convB12_kernel(
    const bf16* __restrict__ temp, const u32* __restrict__ rowstart,
    bf16* __restrict__ y1, bf16* __restrict__ y2b, float* __restrict__ sums2,
    int chunk, int CH)
{
    __shared__ float bnacc[256];
    int tid = threadIdx.x;
    bnacc[tid] = 0.f;
    __syncthreads();
    int lane = tid & 63;
    int half = lane >> 5;
    int l32  = lane & 31;
    int wid = blockIdx.x * 4 + (tid >> 6);
    int nw  = gridDim.x * 4;
    u32 cb = rowstart[(long)chunk * CH];
    int npair = (CH + 1) >> 1;
    float bs[8] = {0,0,0,0,0,0,0,0}, bq[8] = {0,0,0,0,0,0,0,0};

    for (int r2 = wid; r2 < npair; r2 += nw) {
        int ol = r2 * 2 + half;
        if (ol >= CH) continue;
        long o = (long)chunk * CH + ol;
        u32 rs = rowstart[o], re = rowstart[o + 1];
        float a[8] = {0,0,0,0,0,0,0,0};
        for (u32 p = rs; p < re; p += 4) {
            #pragma unroll
            for (int u = 0; u < 4; u++) {
                if (p + u < re) {
                    bf16x8 v = *(const bf16x8*)(temp + (size_t)(p + u - cb) * 256 + l32 * 8);
                    #pragma unroll
                    for (int j = 0; j < 8; j++) a[j] += (float)v[j];
                }
            }
        }
        bf16x8 h;
        #pragma unroll
        for (int j = 0; j < 8; j++) h[j] = (bf16)a[j];
        if (l32 < 16) {
            #pragma unroll
            for (int j = 0; j < 8; j++) { bs[j] += a[j]; bq[j] += a[j] * a[j]; }
            *(bf16x8*)(y1 + o * COUT + l32 * 8) = h;
        } else {
            *(bf16x8*)(y2b + o * COUT + (l32 - 16) * 8) = h;
        }
    }
    if (l32 < 16) {
        #pragma unroll
        for (int j = 0; j < 8; j++) {
            atomicAdd(&bnacc[l32 * 8 + j], bs[j]);
            atomicAdd(&bnacc[128 + l32 * 8 + j], bq[j]);
        }
    }
    __syncthreads();
    atomicAdd(&sums2[tid], bnacc[tid]);
}

// ==================== submanifold phase A (BN2+ReLU fused in gather) ============
// 2x2 wave split: wave (wr,wc): rows wr*32..+32, cols wc*64..+64
__global__ __launch_bounds__(256) void convAs_kernel(
    const bf16* __restrict__ y1, const float* __restrict__ Ws, const float* __restrict__ ss2,
    const u32* __restrict__ listIn, const u32* __restrict__ listDst,
    const u32* __restrict__ startKC, const u32* __restrict__ rowstart,
    bf16* __restrict__ temp, int chunk, int C, int CH)
{
    int k    = blockIdx.y;
    int tid  = threadIdx.x;
    int wave = tid >> 6, lane = tid & 63;
    int wr = wave >> 1, wc = wave & 1;

    int bin = k * C + chunk;
    u32 lo = startKC[bin], hi = startKC[bin + 1];
    u32 ntiles = (hi - lo + 63) >> 6;
    u32 t0 = blockIdx.x * ATILES;
    if (t0 >= ntiles) return;
    u32 chunk_base = rowstart[(long)chunk * CH];

    __shared__ bf16 As[64 * 128];
    __shared__ bf16 stage[4][32 * 64];
    __shared__ u32 s_dst[64];
    __shared__ float s_sc[128], s_sh[128];
    char* asb = (char*)As;
    char* stb = (char*)stage[wave];

    if (tid < 128) { s_sc[tid] = ss2[tid]; s_sh[tid] = ss2[128 + tid]; }

    int l15 = lane & 15;
    int kr0 = (lane >> 4) * 8;
    const float* Wk = Ws + (long)k * COUT * COUT;
    int nbase = wc * 64;
    int mbase = wr * 32;

    bf16x8 bfrag[4][4];
    #pragma unroll
    for (int ks = 0; ks < 4; ks++)
        #pragma unroll
        for (int nf = 0; nf < 4; nf++) {
            const float* p = Wk + (long)(ks * 32 + kr0) * COUT + nbase + nf * 16 + l15;
            bf16x8 b;
            #pragma unroll
            for (int j = 0; j < 8; j++) b[j] = (bf16)p[(long)j * COUT];
            bfrag[ks][nf] = b;
        }

    int grow = tid >> 2, gpart = tid & 3;
    int rbase = (lane >> 4) * 4;

    __syncthreads();   // s_sc/s_sh ready

    for (int t = 0; t < ATILES; t++) {
        u32 tile = t0 + t;
        if (tile >= ntiles) break;
        u32 pos0 = lo + tile * 64;

        if (tid < 64) {
            u32 p = pos0 + tid;
            s_dst[tid] = (p < hi) ? (listDst[p] - chunk_base) : 0xFFFFFFFFu;
        }
        {
            u32 p = pos0 + grow;
            u32 in = (p < hi) ? listIn[p] : 0u;
            const bf16* src = y1 + (long)in * COUT + gpart * 32;
            #pragma unroll
            for (int q = 0; q < 4; q++) {
                bf16x8 v = *(const bf16x8*)(src + q * 8);
                int c0 = gpart * 32 + q * 8;
                bf16x8 h;
                #pragma unroll
                for (int j = 0; j < 8; j++)
                    h[j] = (bf16)fmaxf((float)v[j] * s_sc[c0 + j] + s_sh[c0 + j], 0.f);
                int boff = (grow * 256 + c0 * 2) ^ ((grow & 7) << 4);
                *(bf16x8*)(asb + boff) = h;
            }
        }
        __syncthreads();

        f32x4 acc[2][4];
        #pragma unroll
        for (int m = 0; m < 2; m++)
            #pragma unroll
            for (int n = 0; n < 4; n++) acc[m][n] = (f32x4)(0.f);

        #pragma unroll
        for (int ks = 0; ks < 4; ks++) {
            bf16x8 af[2];
            #pragma unroll
            for (int m = 0; m < 2; m++) {
                int row = mbase + m * 16 + l15;
                int boff = (row * 256 + (ks * 32 + kr0) * 2) ^ ((row & 7) << 4);
                af[m] = *(bf16x8*)(asb + boff);
            }
            #pragma unroll
            for (int m = 0; m < 2; m++)
                #pragma unroll
                for (int nf = 0; nf < 4; nf++)
                    acc[m][nf] = __builtin_amdgcn_mfma_f32_16x16x32_bf16(
                        af[m], bfrag[ks][nf], acc[m][nf], 0, 0, 0);
        }

        // ---- stage (per-wave, 32 rows x 64 cols) ----
        #pragma unroll
        for (int m = 0; m < 2; m++)
            #pragma unroll
            for (int nf = 0; nf < 4; nf++)
                #pragma unroll
                for (int j = 0; j < 4; j++) {
                    int r = m * 16 + rbase + j;
                    int col = nf * 16 + l15;
                    int soff = (r * 128 + col * 2) ^ (((r >> 2) & 7) << 4);
                    *(bf16*)(stb + soff) = (bf16)acc[m][nf][j];
                }
        // ---- stores: 8 rows x 128B per instr, 4 iters for 32 rows ----
        #pragma unroll
        for (int i = 0; i < 4; i++) {
            int r = i * 8 + (lane >> 3);
            u32 dst = s_dst[mbase + r];
            if (dst != 0xFFFFFFFFu) {
                int soff = (r * 128 + ((lane & 7) * 16)) ^ (((r >> 2) & 7) << 4);
                int4 v = *(int4*)(stb + soff);
                *(int4*)((char*)(temp + (size_t)dst * 128) + nbase * 2 + (lane & 7) * 16) = v;
            }
        }
        __syncthreads();
    }
}

// ==================== submanifold phase B: out = y2b + segsum, MLP x4 =============
// half-wave per row; l32 covers 128 channels via bf16x4 / float4.
__global__ __launch_bounds__(256) void convBs_kernel(
    const bf16* __restrict__ temp, const u32* __restrict__ rowstart,
    const bf16* __restrict__ y2b, float* __restrict__ out, int chunk, int CH)
{
    int tid = threadIdx.x;
    int lane = tid & 63;
    int half = lane >> 5;
    int l32  = lane & 31;
    int wid = blockIdx.x * 4 + (tid >> 6);
    int nw  = gridDim.x * 4;
    u32 cb = rowstart[(long)chunk * CH];
    int npair = (CH + 1) >> 1;

    for (int r2 = wid; r2 < npair; r2 += nw) {
        int ol = r2 * 2 + half;
        if (ol >= CH) continue;
        long o = (long)chunk * CH + ol;
        u32 rs = rowstart[o], re = rowstart[o + 1];
        float a[4] = {0,0,0,0};
        for (u32 p = rs; p < re; p += 4) {
            #pragma unroll
            for (int u = 0; u < 4; u++) {
                if (p + u < re) {
                    bf16x4 v = *(const bf16x4*)(temp + (size_t)(p + u - cb) * 128 + l32 * 4);
                    #pragma unroll
                    for (int j = 0; j < 4; j++) a[j] += (float)v[j];
                }
            }
        }
        bf16x4 yv = *(const bf16x4*)(y2b + o * COUT + l32 * 4);
        float4 w = make_float4(a[0] + (float)yv[0], a[1] + (float)yv[1],
                               a[2] + (float)yv[2], a[3] + (float)yv[3]);
        *(float4*)(out + o * COUT + l32 * 4) = w;
    }
}

// ==================== fallback (round-1 atomic path) ====================
__global__ __launch_bounds__(256) void conv12_atomic_kernel(
    const float* __restrict__ x,
    const float* __restrict__ W1, const float* __restrict__ W2,
    const int* __restrict__ in_idx, const int* __restrict__ out_idx,
    const float* __restrict__ ss1,
    float* __restrict__ y1, float* __restrict__ y2)
{
    int k    = blockIdx.y;
    int tid  = threadIdx.x;
    int wave = tid >> 6, lane = tid & 63;

    __shared__ bf16 As[64 * 64];
    __shared__ int  s_out[64];
    __shared__ float s_sc[64], s_sh[64];
    char* asb = (char*)As;

    if (tid < 64) { s_sc[tid] = ss1[tid]; s_sh[tid] = ss1[64 + tid]; }

    const float* Wk = ((wave & 2) ? W2 : W1) + (long)k * CIN * COUT;
    int nbase = (wave & 1) * 64;
    int l15 = lane & 15;
    int kr0 = (lane >> 4) * 8;

    bf16x8 bfrag[2][4];
    #pragma unroll
    for (int ks = 0; ks < 2; ks++)
        #pragma unroll
        for (int nf = 0; nf < 4; nf++) {
            const float* p = Wk + (long)(ks * 32 + kr0) * COUT + nbase + nf * 16 + l15;
            bf16x8 b;
            #pragma unroll
            for (int j = 0; j < 8; j++) b[j] = (bf16)p[(long)j * COUT];
            bfrag[ks][nf] = b;
        }

    const int* in_k  = in_idx  + k * R_PAIRS;
    const int* out_k = out_idx + k * R_PAIRS;
    float* ybase = (wave & 2) ? y2 : y1;

    int grow = tid >> 2;
    int gcol = (tid & 3) * 16;

    __syncthreads();

    for (int t = 0; t < OLD_TILES; t++) {
        int pair0 = blockIdx.x * (OLD_TILES * 64) + t * 64;
        {
            int p = pair0 + grow;
            bool valid = p < R_PAIRS;
            long src = valid ? (long)in_k[p] : 0;
            const float4* xr = (const float4*)(x + src * CIN + gcol);
            #pragma unroll
            for (int g = 0; g < 2; g++) {
                float4 va = make_float4(0, 0, 0, 0), vb = va;
                if (valid) { va = xr[g * 2]; vb = xr[g * 2 + 1]; }
                float f[8] = {va.x, va.y, va.z, va.w, vb.x, vb.y, vb.z, vb.w};
                bf16x8 h;
                #pragma unroll
                for (int j = 0; j < 8; j++) {
                    int c = gcol + g * 8 + j;
                    h[j] = (bf16)fmaxf(f[j] * s_sc[c] + s_sh[c], 0.f);
                }
                int boff = ((grow * 128) + (gcol + g * 8) * 2) ^ ((grow & 7) << 4);
                *(bf16x8*)(asb + boff) = h;
            }
        }
        if (tid < 64) {
            int p = pair0 + tid;
            s_out[tid] = (p < R_PAIRS) ? out_k[p] : -1;
        }
        __syncthreads();

        f32x4 acc[4][4];
        #pragma unroll
        for (int m = 0; m < 4; m++)
            #pragma unroll
            for (int n = 0; n < 4; n++) acc[m][n] = (f32x4)(0.f);

        #pragma unroll
        for (int ks = 0; ks < 2; ks++) {
            bf16x8 af[4];
            #pragma unroll
            for (int m = 0; m < 4; m++) {
                int row = m * 16 + l15;
                int boff = (row * 128 + (ks * 32 + kr0) * 2) ^ ((row & 7) << 4);
                af[m] = *(bf16x8*)(asb + boff);
            }
            #pragma unroll
            for (int m = 0; m < 4; m++)
                #pragma unroll
                for (int nf = 0; nf < 4; nf++)
                    acc[m][nf] = __builtin_amdgcn_mfma_f32_16x16x32_bf16(
                        af[m], bfrag[ks][nf], acc[m][nf], 0, 0, 0);
        }

        int rbase = (lane >> 4) * 4;
        #pragma unroll
        for (int m = 0; m < 4; m++)
            #pragma unroll
            for (int j = 0; j < 4; j++) {
                int o = s_out[m * 16 + rbase + j];
                if (o >= 0)
                    #pragma unroll
                    for (int nf = 0; nf < 4; nf++)
                        atomicAdd(&ybase[(long)o * COUT + nbase + nf * 16 + l15],
                                  acc[m][nf][j]);
            }
        __syncthreads();
    }
}

__global__ __launch_bounds__(256) void convs_atomic_kernel(
    const float* __restrict__ y1,
    const float* __restrict__ Ws,
    const int* __restrict__ in_idx, const int* __restrict__ out_idx,
    const float* __restrict__ ss2,
    float* __restrict__ out)
{
    int k    = blockIdx.y;
    int tid  = threadIdx.x;
    int wave = tid >> 6, lane = tid & 63;

    __shared__ bf16 As[64 * 128];
    __shared__ int  s_out[64];
    __shared__ float s_sc[128], s_sh[128];
    char* asb = (char*)As;

    if (tid < 128) { s_sc[tid] = ss2[tid]; s_sh[tid] = ss2[128 + tid]; }

    const float* Wk = Ws + (long)k * COUT * COUT;
    int nbase = wave * 32;
    int l15 = lane & 15;
    int kr0 = (lane >> 4) * 8;

    bf16x8 bfrag[4][2];
    #pragma unroll
    for (int ks = 0; ks < 4; ks++)
        #pragma unroll
        for (int nf = 0; nf < 2; nf++) {
            const float* p = Wk + (long)(ks * 32 + kr0) * COUT + nbase + nf * 16 + l15;
            bf16x8 b;
            #pragma unroll
            for (int j = 0; j < 8; j++) b[j] = (bf16)p[(long)j * COUT];
            bfrag[ks][nf] = b;
        }

    const int* in_k  = in_idx  + k * R_PAIRS;
    const int* out_k = out_idx + k * R_PAIRS;

    int grow = tid >> 2;
    int gcol = (tid & 3) * 32;

    __syncthreads();

    for (int t = 0; t < OLD_TILES; t++) {
        int pair0 = blockIdx.x * (OLD_TILES * 64) + t * 64;
        {
            int p = pair0 + grow;
            bool valid = p < R_PAIRS;
            long src = valid ? (long)in_k[p] : 0;
            const float4* yr = (const float4*)(y1 + src * COUT + gcol);
            #pragma unroll
            for (int g = 0; g < 4; g++) {
                float4 va = make_float4(0, 0, 0, 0), vb = va;
                if (valid) { va = yr[g * 2]; vb = yr[g * 2 + 1]; }
                float f[8] = {va.x, va.y, va.z, va.w, vb.x, vb.y, vb.z, vb.w};
                bf16x8 h;
                #pragma unroll
                for (int j = 0; j < 8; j++) {
                    int c = gcol + g * 8 + j;
                    h[j] = (bf16)fmaxf(f[j] * s_sc[c] + s_sh[c], 0.f);
                }
                int boff = (grow * 256 + (gcol + g * 8) * 2) ^ ((grow & 7) << 4);
                *(bf16x8*)(asb + boff) = h;
            }
        }
        if (tid < 64) {
            int p = pair0 + tid;
            s_out[tid] = (p < R_PAIRS) ? out_k[p] : -1;
        }
        __syncthreads();

        f32x4 acc[4][2];
        #pragma unroll
        for (int m = 0; m < 4; m++)
            #pragma unroll
            for (int n = 0; n < 2; n++) acc[m][n] = (f32x4)(0.f);

        #pragma unroll
        for (int ks = 0; ks < 4; ks++) {
            bf16x8 af[4];
            #pragma unroll
            for (int m = 0; m < 4; m++) {
                int row = m * 16 + l15;
                int boff = (row * 256 + (ks * 32 + kr0) * 2) ^ ((row & 7) << 4);
                af[m] = *(bf16x8*)(asb + boff);
            }
            #pragma unroll
            for (int m = 0; m < 4; m++)
                #pragma unroll
                for (int nf = 0; nf < 2; nf++)
                    acc[m][nf] = __builtin_amdgcn_mfma_f32_16x16x32_bf16(
                        af[m], bfrag[ks][nf], acc[m][nf], 0, 0, 0);
        }

        int rbase = (lane >> 4) * 4;
        #pragma unroll
        for (int m = 0; m < 4; m++)
            #pragma unroll
            for (int j = 0; j < 4; j++) {
                int o = s_out[m * 16 + rbase + j];
                if (o >= 0)
                    #pragma unroll
                    for (int nf = 0; nf < 2; nf++)
                        atomicAdd(&out[(long)o * COUT + nbase + nf * 16 + l15],
                                  acc[m][nf][j]);
            }
        __syncthreads();
    }
}

// ==================== host ====================
extern "C" void kernel_launch(void* const* d_in, const int* in_sizes, int n_in,
                              void* d_out, int out_size, void* d_ws, size_t ws_size,
                              hipStream_t stream) {
    const float* x       = (const float*)d_in[0];
    const float* gamma1  = (const float*)d_in[1];
    const float* beta1   = (const float*)d_in[2];
    const float* gamma2  = (const float*)d_in[3];
    const float* beta2   = (const float*)d_in[4];
    const float* W1      = (const float*)d_in[5];
    const float* Ws      = (const float*)d_in[6];
    const float* W2      = (const float*)d_in[7];
    const int*   in_idx1   = (const int*)d_in[8];
    const int*   out_idx1  = (const int*)d_in[9];
    const int*   in_idx_s  = (const int*)d_in[10];
    const int*   out_idx_s = (const int*)d_in[11];

    float* out = (float*)d_out;
    char*  ws  = (char*)d_ws;

    auto a256 = [](size_t v) { return (v + 255) & ~(size_t)255; };

    size_t off_y1      = 0;                                    // bf16 y1: 32 MB
    size_t off_sums    = a256(off_y1 + 32000000);              // 4 KB stats
    size_t off_x1      = a256(off_sums + 4096);                // bf16 x1: 64 MB
    size_t off_y2b     = a256(off_x1 + 64000000);              // bf16 y2b: 32 MB
    size_t off_countO  = a256(off_y2b + 32000000);             // 500 KB
    size_t off_cursorO = a256(off_countO + 4 * N_OUT);         // 500 KB
    size_t off_rows    = a256(off_cursorO + 4 * N_OUT);        // rowstart: 500 KB
    size_t off_bsum    = a256(off_rows + 4 * (N_OUT + 1));     // 1 KB
    size_t off_kc      = a256(off_bsum + 1024);                // 1 KB
    size_t off_listIn  = a256(off_kc + 1024);                  // 2 MB
    size_t off_listDst = a256(off_listIn + 4 * NPAIRS);        // 2 MB
    size_t off_temp    = a256(off_listDst + 4 * NPAIRS);

    int C = 0;
    const int cands[4] = {1, 2, 4, 8};
    for (int ci = 0; ci < 4; ci++) {
        size_t cap = (size_t)(NPAIRS / cands[ci]) + 8192;
        if (off_temp + cap * 512 <= ws_size) { C = cands[ci]; break; }
    }

    if (C == 0) {
        // -------- fallback: atomic path (needs only 64 MB + 4 KB) --------
        float* y1f   = (float*)ws;
        float* stats = y1f + (long)N_OUT * COUT;
        float* sums1 = stats;
        float* ss1   = stats + 128;
        float* sums2 = stats + 256;
        float* ss2   = stats + 512;

        hipMemsetAsync(d_out, 0, (size_t)N_OUT * COUT * 4, stream);
        hipMemsetAsync(d_ws,  0, (size_t)N_OUT * COUT * 4 + 768 * 4, stream);

        bn_stats_kernel<64><<<1024, 256, 0, stream>>>(x, N_IN, sums1);
        bn_finalize_kernel<64><<<1, 64, 0, stream>>>(sums1, gamma1, beta1, 1.f / N_IN, ss1);

        dim3 cgrid((R_PAIRS + OLD_TILES * 64 - 1) / (OLD_TILES * 64), K_OFF);
        conv12_atomic_kernel<<<cgrid, 256, 0, stream>>>(x, W1, W2, in_idx1, out_idx1, ss1, y1f, out);

        bn_stats_kernel<128><<<1024, 256, 0, stream>>>(y1f, N_OUT, sums2);
        bn_finalize_kernel<128><<<1, 128, 0, stream>>>(sums2, gamma2, beta2, 1.f / N_OUT, ss2);

        convs_atomic_kernel<<<cgrid, 256, 0, stream>>>(y1f, Ws, in_idx_s, out_idx_s, ss2, out);
        return;
    }

    int CH = N_OUT / C;

    bf16*  y1      = (bf16*)(ws + off_y1);
    float* sums1   = (float*)(ws + off_sums);     // [256]
    float* ss1     = sums1 + 256;                 // [256]
    float* sums2   = sums1 + 512;                 // [256]
    float* ss2     = sums1 + 768;                 // [256]
    bf16*  x1      = (bf16*)(ws + off_x1);
    bf16*  y2b     = (bf16*)(ws + off_y2b);
    u32*   countO  = (u32*)(ws + off_countO);
    u32*   cursorO = (u32*)(ws + off_cursorO);
    u32*   rows    = (u32*)(ws + off_rows);
    u32*   bsum    = (u32*)(ws + off_bsum);
    u32*   kc      = (u32*)(ws + off_kc);         // cnt[0..63], start[64..], cursor[160..]
    u32*   listIn  = (u32*)(ws + off_listIn);
    u32*   listDst = (u32*)(ws + off_listDst);
    bf16*  temp    = (bf16*)(ws + off_temp);

    int nbKC = K_OFF * C;
    int maxseg = R_PAIRS / ((C + 1) / 2) + 2048;   // C=1: full k-segment 62500
    if (C == 1) maxseg = R_PAIRS;
    int tilesA = ((maxseg + 63) / 64 + ATILES - 1) / ATILES;
    dim3 gA(tilesA, K_OFF);

    // ---- BN1 stats + apply -> x1 (bf16) ----
    hipMemsetAsync(sums1, 0, 4096, stream);
    bn_stats_kernel<64><<<1024, 256, 0, stream>>>(x, N_IN, sums1);
    bn_finalize_kernel<64><<<1, 64, 0, stream>>>(sums1, gamma1, beta1, 1.f / N_IN, ss1);
    bn_apply_f32_kernel<64><<<4096, 256, 0, stream>>>(x, ss1, x1, (long)N_IN * CIN / 8);

    // ---- rulebook 1: out-major sort + (k,chunk) lists ----
    hipMemsetAsync(countO, 0, 4 * N_OUT, stream);
    hipMemsetAsync(kc, 0, 1024, stream);
    histO_kernel<<<512, 256, 0, stream>>>(out_idx1, countO, kc, C, CH);
    scan1_kernel<<<NSB_OUT, 256, 0, stream>>>(countO, bsum, N_OUT);
    scan2_kernel<<<1, 256, 0, stream>>>(bsum, rows, NSB_OUT, N_OUT);
    scan3_kernel<<<NSB_OUT, 256, 0, stream>>>(countO, bsum, rows, N_OUT);
    scanKC_kernel<<<1, 1, 0, stream>>>(kc, nbKC);
    hipMemsetAsync(cursorO, 0, 4 * N_OUT, stream);
    buildlists_kernel<<<(NPAIRS + 255) / 256, 256, 0, stream>>>(
        in_idx1, out_idx1, rows, cursorO, kc, listIn, listDst, C, CH);

    // ---- conv1+conv2 per chunk ----
    for (int c = 0; c < C; c++) {
        convA12_kernel<<<gA, 256, 0, stream>>>(x1, W1, W2, listIn, listDst,
                                               kc + 64, rows, temp, c, C, CH);
        convB12_kernel<<<2048, 256, 0, stream>>>(temp, rows, y1, y2b, sums2, c, CH);
    }

    // ---- BN2 finalize (stats fused into convB12) ----
    bn_finalize_kernel<128><<<1, 128, 0, stream>>>(sums2, gamma2, beta2, 1.f / N_OUT, ss2);

    // ---- rulebook s: out-major sort + lists (reuse buffers) ----
    hipMemsetAsync(countO, 0, 4 * N_OUT, stream);
    hipMemsetAsync(kc, 0, 1024, stream);
    histO_kernel<<<512, 256, 0, stream>>>(out_idx_s, countO, kc, C, CH);
    scan1_kernel<<<NSB_OUT, 256, 0, stream>>>(countO, bsum, N_OUT);
    scan2_kernel<<<1, 256, 0, stream>>>(bsum, rows, NSB_OUT, N_OUT);
    scan3_kernel<<<NSB_OUT, 256, 0, stream>>>(countO, bsum, rows, N_OUT);
    scanKC_kernel<<<1, 1, 0, stream>>>(kc, nbKC);
    hipMemsetAsync(cursorO, 0, 4 * N_OUT, stream);
    buildlists_kernel<<<(NPAIRS + 255) / 256, 256, 0, stream>>>(
        in_idx_s, out_idx_s, rows, cursorO, kc, listIn, listDst, C, CH);

    // ---- submanifold conv per chunk (BN2+ReLU fused into gather) ----
    for (int c = 0; c < C; c++) {
        convAs_kernel<<<gA, 256, 0, stream>>>(y1, Ws, ss2, listIn, listDst,
                                              kc + 64, rows, temp, c, C, CH);
        convBs_kernel<<<2048, 256, 0, stream>>>(temp, rows, y2b, out, c, CH);
    }
}